// Round 1
// baseline (253.697 us; speedup 1.0000x reference)
//
#include <hip/hip_runtime.h>
#include <stdint.h>

typedef __attribute__((ext_vector_type(8))) short short8;
typedef __attribute__((ext_vector_type(4))) float floatx4;

#define HD 64
#define D_IN 1024
#define TLEN 4096
#define NB 4
#define LDK 72   // LDS row stride in bf16 elems: 144 B, 16B-aligned, conflict-free-ish

__device__ __forceinline__ short f2bf(float f) {
    union { float f; uint32_t u; } v{f};
    uint32_t u = v.u;
    uint32_t r = (u + 0x7FFFu + ((u >> 16) & 1u)) >> 16;
    return (short)r;
}

// ---------------- kernel 0: W -> W^T bf16 in ws ----------------
// wt[mat][n][k], n in [0,64), k in [0,1024)
__global__ __launch_bounds__(256) void prep_w(const float* __restrict__ Wk,
                                              const float* __restrict__ Wq,
                                              const float* __restrict__ Wv,
                                              short* __restrict__ wt) {
    int i = blockIdx.x * 256 + threadIdx.x;      // 3*64*1024 = 196608
    int k = i & 1023;
    int n = (i >> 10) & 63;
    int mat = i >> 16;
    const float* W = (mat == 0) ? Wk : ((mat == 1) ? Wq : Wv);
    wt[(size_t)mat * 65536 + (size_t)n * 1024 + k] = f2bf(W[(size_t)k * 64 + n]);
}

// ---------------- kernel 1: fused QKV projection ----------------
// 64 rows/block, all 3 output matrices. Outputs bf16 k,q,v in ws.
__global__ __launch_bounds__(256) void proj(const float* __restrict__ x,
                                            const float* __restrict__ bk,
                                            const float* __restrict__ bq,
                                            const float* __restrict__ bv,
                                            const short* __restrict__ wt,
                                            short* __restrict__ ko,
                                            short* __restrict__ qo,
                                            short* __restrict__ vo) {
    __shared__ short xs[64 * LDK];
    __shared__ short wls[3][64 * LDK];

    int tid = threadIdx.x;
    int wave = tid >> 6, lane = tid & 63;
    int quad = lane >> 4, l16 = lane & 15;
    int row0 = blockIdx.x * 64;   // row in flattened [B*T, D] x

    floatx4 acc[3][4];
#pragma unroll
    for (int m = 0; m < 3; m++)
#pragma unroll
        for (int nt = 0; nt < 4; nt++) acc[m][nt] = (floatx4){0.f, 0.f, 0.f, 0.f};

    for (int k0 = 0; k0 < D_IN; k0 += 64) {
        // stage x tile 64x64 fp32 -> bf16  (1024 float4 units)
#pragma unroll
        for (int it = 0; it < 4; it++) {
            int i = tid + it * 256;
            int r = i >> 4, c4 = i & 15;
            const float4 f = reinterpret_cast<const float4*>(x + (size_t)(row0 + r) * D_IN + k0)[c4];
            short* dst = &xs[r * LDK + c4 * 4];
            dst[0] = f2bf(f.x); dst[1] = f2bf(f.y); dst[2] = f2bf(f.z); dst[3] = f2bf(f.w);
        }
        // stage W^T tiles: 3 mats x 64 n x 64 k (bf16, plain 16B copies); 1536 units of 8 shorts
#pragma unroll
        for (int it = 0; it < 6; it++) {
            int u = tid + it * 256;
            int mat = u >> 9;
            int n = (u >> 3) & 63;
            int c = u & 7;
            const int4 val = *reinterpret_cast<const int4*>(wt + (size_t)mat * 65536 + (size_t)n * 1024 + k0 + c * 8);
            *reinterpret_cast<int4*>(&wls[mat][n * LDK + c * 8]) = val;
        }
        __syncthreads();
#pragma unroll
        for (int ks = 0; ks < 2; ks++) {
            short8 a = *reinterpret_cast<const short8*>(&xs[(wave * 16 + l16) * LDK + ks * 32 + quad * 8]);
#pragma unroll
            for (int mat = 0; mat < 3; mat++)
#pragma unroll
                for (int nt = 0; nt < 4; nt++) {
                    short8 b = *reinterpret_cast<const short8*>(&wls[mat][(nt * 16 + l16) * LDK + ks * 32 + quad * 8]);
                    acc[mat][nt] = __builtin_amdgcn_mfma_f32_16x16x32_bf16(a, b, acc[mat][nt], 0, 0, 0);
                }
        }
        __syncthreads();
    }

    const float* bias[3] = {bk, bq, bv};
    short* outp[3] = {ko, qo, vo};
#pragma unroll
    for (int mat = 0; mat < 3; mat++) {
#pragma unroll
        for (int nt = 0; nt < 4; nt++) {
            int col = nt * 16 + l16;
            float bv_ = bias[mat][col];
#pragma unroll
            for (int reg = 0; reg < 4; reg++) {
                int r = row0 + wave * 16 + quad * 4 + reg;
                outp[mat][(size_t)r * HD + col] = f2bf(acc[mat][nt][reg] + bv_);
            }
        }
    }
}

// ---------------- kernel 2: flash causal attention ----------------
// out[b,t,:] = softmax_s( k[t]*q[s]/8, s<=t ) @ v
// Qf := k array, Kf := q array, Vf := v array (the reference's swap).
__global__ __launch_bounds__(256) void attn(const short* __restrict__ kb,
                                            const short* __restrict__ qb,
                                            const short* __restrict__ vb,
                                            float* __restrict__ out) {
    __shared__ short Ks[64 * LDK];
    __shared__ short Vt[64 * LDK];   // transposed: Vt[h][s]
    __shared__ short Ps[64 * LDK];

    int tid = threadIdx.x;
    int wave = tid >> 6, lane = tid & 63;
    int quad = lane >> 4, l16 = lane & 15;

    // high-work (large tile index) blocks first for load balance
    int tile = 63 - (blockIdx.x >> 2);
    int batch = blockIdx.x & 3;
    int t0 = tile * 64;
    size_t base = (size_t)batch * TLEN * HD;

    // Q fragments (rows = k-vectors), held in registers for the whole block
    short8 qf[2];
    {
        int trow = t0 + wave * 16 + l16;
#pragma unroll
        for (int ks = 0; ks < 2; ks++)
            qf[ks] = *reinterpret_cast<const short8*>(kb + base + (size_t)trow * HD + ks * 32 + quad * 8);
    }

    floatx4 o_acc[4];
#pragma unroll
    for (int ht = 0; ht < 4; ht++) o_acc[ht] = (floatx4){0.f, 0.f, 0.f, 0.f};
    float m_old[4] = {-INFINITY, -INFINITY, -INFINITY, -INFINITY};
    float l_sum[4] = {0.f, 0.f, 0.f, 0.f};
    const float sl2e = 0.18033688011112042f;  // (1/sqrt(64)) * log2(e)

    int ntile_kv = tile + 1;
    for (int j = 0; j < ntile_kv; j++) {
        int s0 = j * 64;
        // stage Kf tile (rows s, cols h) from q array: 512 units of 8 bf16
#pragma unroll
        for (int it = 0; it < 2; it++) {
            int i = tid + it * 256;
            int r = i >> 3, c = i & 7;
            const int4 val = *reinterpret_cast<const int4*>(qb + base + (size_t)(s0 + r) * HD + c * 8);
            *reinterpret_cast<int4*>(&Ks[r * LDK + c * 8]) = val;
        }
        // stage V transposed: Vt[h][s]
#pragma unroll
        for (int it = 0; it < 4; it++) {
            int i = tid + it * 256;
            int s = i >> 4, h4 = (i & 15) * 4;
            uint2 d = *reinterpret_cast<const uint2*>(vb + base + (size_t)(s0 + s) * HD + h4);
            Vt[(h4 + 0) * LDK + s] = (short)(d.x & 0xFFFF);
            Vt[(h4 + 1) * LDK + s] = (short)(d.x >> 16);
            Vt[(h4 + 2) * LDK + s] = (short)(d.y & 0xFFFF);
            Vt[(h4 + 3) * LDK + s] = (short)(d.y >> 16);
        }
        __syncthreads();

        // S = Qf * Kf^T  (16 rows per wave x 64 cols)
        floatx4 sacc[4];
#pragma unroll
        for (int nt = 0; nt < 4; nt++) sacc[nt] = (floatx4){0.f, 0.f, 0.f, 0.f};
#pragma unroll
        for (int ks = 0; ks < 2; ks++)
#pragma unroll
            for (int nt = 0; nt < 4; nt++) {
                short8 b = *reinterpret_cast<const short8*>(&Ks[(nt * 16 + l16) * LDK + ks * 32 + quad * 8]);
                sacc[nt] = __builtin_amdgcn_mfma_f32_16x16x32_bf16(qf[ks], b, sacc[nt], 0, 0, 0);
            }

        // scale to log2 domain + causal mask (diagonal tile only)
        float sv[4][4];
        bool diag = (j == ntile_kv - 1);
#pragma unroll
        for (int nt = 0; nt < 4; nt++) {
            int s_g = s0 + nt * 16 + l16;
#pragma unroll
            for (int reg = 0; reg < 4; reg++) {
                float v = sacc[nt][reg] * sl2e;
                int t_g = t0 + wave * 16 + quad * 4 + reg;
                if (diag && s_g > t_g) v = -INFINITY;
                sv[nt][reg] = v;
            }
        }

        // online softmax: row stats within each quad (16 lanes hold one row's 64 cols)
        float m_new[4], alpha[4];
#pragma unroll
        for (int reg = 0; reg < 4; reg++) {
            float mp = fmaxf(fmaxf(sv[0][reg], sv[1][reg]), fmaxf(sv[2][reg], sv[3][reg]));
#pragma unroll
            for (int off = 8; off >= 1; off >>= 1) mp = fmaxf(mp, __shfl_xor(mp, off, 16));
            m_new[reg] = fmaxf(m_old[reg], mp);
            alpha[reg] = __builtin_amdgcn_exp2f(m_old[reg] - m_new[reg]);
            m_old[reg] = m_new[reg];
        }
        float pv[4][4];
#pragma unroll
        for (int reg = 0; reg < 4; reg++) {
            float s = 0.f;
#pragma unroll
            for (int nt = 0; nt < 4; nt++) {
                pv[nt][reg] = __builtin_amdgcn_exp2f(sv[nt][reg] - m_new[reg]);
                s += pv[nt][reg];
            }
#pragma unroll
            for (int off = 8; off >= 1; off >>= 1) s += __shfl_xor(s, off, 16);
            l_sum[reg] = l_sum[reg] * alpha[reg] + s;
        }
        // rescale O accumulator
#pragma unroll
        for (int ht = 0; ht < 4; ht++)
#pragma unroll
            for (int reg = 0; reg < 4; reg++) o_acc[ht][reg] *= alpha[reg];

        // P (C-layout) -> LDS in A-layout order
#pragma unroll
        for (int nt = 0; nt < 4; nt++)
#pragma unroll
            for (int reg = 0; reg < 4; reg++)
                Ps[(wave * 16 + quad * 4 + reg) * LDK + nt * 16 + l16] = f2bf(pv[nt][reg]);
        __syncthreads();

        // O += P @ V
#pragma unroll
        for (int ks = 0; ks < 2; ks++) {
            short8 a = *reinterpret_cast<const short8*>(&Ps[(wave * 16 + l16) * LDK + ks * 32 + quad * 8]);
#pragma unroll
            for (int ht = 0; ht < 4; ht++) {
                short8 b = *reinterpret_cast<const short8*>(&Vt[(ht * 16 + l16) * LDK + ks * 32 + quad * 8]);
                o_acc[ht] = __builtin_amdgcn_mfma_f32_16x16x32_bf16(a, b, o_acc[ht], 0, 0, 0);
            }
        }
        __syncthreads();
    }

    // epilogue: divide by l, store fp32
    float inv[4];
#pragma unroll
    for (int reg = 0; reg < 4; reg++) inv[reg] = 1.0f / l_sum[reg];
#pragma unroll
    for (int ht = 0; ht < 4; ht++)
#pragma unroll
        for (int reg = 0; reg < 4; reg++) {
            int t = t0 + wave * 16 + quad * 4 + reg;
            out[base + (size_t)t * HD + ht * 16 + l16] = o_acc[ht][reg] * inv[reg];
        }
}

extern "C" void kernel_launch(void* const* d_in, const int* in_sizes, int n_in,
                              void* d_out, int out_size, void* d_ws, size_t ws_size,
                              hipStream_t stream) {
    const float* x  = (const float*)d_in[0];
    const float* Wk = (const float*)d_in[1];
    const float* bk = (const float*)d_in[2];
    const float* Wq = (const float*)d_in[3];
    const float* bq = (const float*)d_in[4];
    const float* Wv = (const float*)d_in[5];
    const float* bv = (const float*)d_in[6];
    float* out = (float*)d_out;

    const size_t nrow = (size_t)NB * TLEN;            // 16384
    short* ko = (short*)d_ws;                         // bf16 k  [16384,64]
    short* qo = ko + nrow * HD;                       // bf16 q
    short* vo = qo + nrow * HD;                       // bf16 v
    short* wt = vo + nrow * HD;                       // bf16 W^T [3][64][1024]

    prep_w<<<768, 256, 0, stream>>>(Wk, Wq, Wv, wt);
    proj<<<256, 256, 0, stream>>>(x, bk, bq, bv, wt, ko, qo, vo);
    attn<<<256, 256, 0, stream>>>(ko, qo, vo, out);
}

// Round 2
// 203.486 us; speedup vs baseline: 1.2468x; 1.2468x over previous
//
#include <hip/hip_runtime.h>
#include <stdint.h>

typedef __attribute__((ext_vector_type(8))) short short8;
typedef __attribute__((ext_vector_type(4))) float floatx4;

#define HD 64
#define D_IN 1024
#define TLEN 4096
#define NB 4
#define LDK 72     // LDS row stride (bf16 elems): 144 B, 16B-aligned
#define PPB 288    // partial slots per batch: sum_{i=0}^{63} ceil((i+1)/8)

__device__ __forceinline__ short f2bf(float f) {
    union { float f; uint32_t u; } v{f};
    uint32_t u = v.u;
    uint32_t r = (u + 0x7FFFu + ((u >> 16) & 1u)) >> 16;
    return (short)r;
}

// ---------------- kernel 0: W -> W^T bf16 in ws ----------------
__global__ __launch_bounds__(256) void prep_w(const float* __restrict__ Wk,
                                              const float* __restrict__ Wq,
                                              const float* __restrict__ Wv,
                                              short* __restrict__ wt) {
    int i = blockIdx.x * 256 + threadIdx.x;      // 3*64*1024 = 196608
    int k = i & 1023;
    int n = (i >> 10) & 63;
    int mat = i >> 16;
    const float* W = (mat == 0) ? Wk : ((mat == 1) ? Wq : Wv);
    wt[(size_t)mat * 65536 + (size_t)n * 1024 + k] = f2bf(W[(size_t)k * 64 + n]);
}

// ---------------- kernel 1: fused QKV projection ----------------
// 32 rows/block, K split across wave pairs, no per-iter barriers.
// k,q stored row-major bf16; v stored TRANSPOSED: vt[b][h][t].
__global__ __launch_bounds__(256) void proj(const float* __restrict__ x,
                                            const float* __restrict__ bk,
                                            const float* __restrict__ bq,
                                            const float* __restrict__ bv,
                                            const short* __restrict__ wt,
                                            short* __restrict__ ko,
                                            short* __restrict__ qo,
                                            short* __restrict__ vt) {
    __shared__ float cacc[2 * 48 * 64];   // [pair][idx][lane]  24 KB
    __shared__ short vs[64 * 40];         // [col][t0..31 + pad] 5 KB

    int tid = threadIdx.x;
    int wave = tid >> 6, lane = tid & 63;
    int quad = lane >> 4, l16 = lane & 15;
    int pairid = wave & 1;     // which 16-row half
    int khalf = wave >> 1;     // which K half
    int rowbase = blockIdx.x * 32;
    int row0 = rowbase + pairid * 16;

    const float* xr = x + (size_t)(row0 + l16) * D_IN;

    floatx4 acc[3][4];
#pragma unroll
    for (int m = 0; m < 3; m++)
#pragma unroll
        for (int nt = 0; nt < 4; nt++) acc[m][nt] = (floatx4){0.f, 0.f, 0.f, 0.f};

#pragma unroll 4
    for (int it = 0; it < 16; ++it) {
        int kb_ = (khalf * 16 + it) * 32 + quad * 8;
        float4 f0 = *reinterpret_cast<const float4*>(xr + kb_);
        float4 f1 = *reinterpret_cast<const float4*>(xr + kb_ + 4);
        short8 a;
        a[0] = f2bf(f0.x); a[1] = f2bf(f0.y); a[2] = f2bf(f0.z); a[3] = f2bf(f0.w);
        a[4] = f2bf(f1.x); a[5] = f2bf(f1.y); a[6] = f2bf(f1.z); a[7] = f2bf(f1.w);
#pragma unroll
        for (int mat = 0; mat < 3; mat++)
#pragma unroll
            for (int nt = 0; nt < 4; nt++) {
                short8 b = *reinterpret_cast<const short8*>(
                    wt + (size_t)mat * 65536 + (size_t)(nt * 16 + l16) * 1024 + kb_);
                acc[mat][nt] = __builtin_amdgcn_mfma_f32_16x16x32_bf16(a, b, acc[mat][nt], 0, 0, 0);
            }
    }

    if (khalf == 1) {
#pragma unroll
        for (int mat = 0; mat < 3; mat++)
#pragma unroll
            for (int nt = 0; nt < 4; nt++)
#pragma unroll
                for (int reg = 0; reg < 4; reg++)
                    cacc[(pairid * 48 + mat * 16 + nt * 4 + reg) * 64 + lane] = acc[mat][nt][reg];
    }
    __syncthreads();
    if (khalf == 0) {
#pragma unroll
        for (int mat = 0; mat < 3; mat++)
#pragma unroll
            for (int nt = 0; nt < 4; nt++)
#pragma unroll
                for (int reg = 0; reg < 4; reg++)
                    acc[mat][nt][reg] += cacc[(pairid * 48 + mat * 16 + nt * 4 + reg) * 64 + lane];
        // k, q row-major stores
#pragma unroll
        for (int mat = 0; mat < 2; mat++) {
            const float* bias = mat ? bq : bk;
            short* op = mat ? qo : ko;
#pragma unroll
            for (int nt = 0; nt < 4; nt++) {
                int col = nt * 16 + l16;
                float bb = bias[col];
#pragma unroll
                for (int reg = 0; reg < 4; reg++)
                    op[(size_t)(row0 + quad * 4 + reg) * HD + col] = f2bf(acc[mat][nt][reg] + bb);
            }
        }
        // v -> LDS transpose buffer
#pragma unroll
        for (int nt = 0; nt < 4; nt++) {
            int col = nt * 16 + l16;
            float bb = bv[col];
#pragma unroll
            for (int reg = 0; reg < 4; reg++)
                vs[col * 40 + pairid * 16 + quad * 4 + reg] = f2bf(acc[2][nt][reg] + bb);
        }
    }
    __syncthreads();
    // cooperative transposed store of v: 64 cols x 32 t
    {
        int col = tid >> 2, tseg = (tid & 3) * 8;
        int4 val = *reinterpret_cast<const int4*>(&vs[col * 40 + tseg]);
        int batch = rowbase >> 12;
        int tloc = (rowbase & 4095) + tseg;
        *reinterpret_cast<int4*>(vt + (size_t)batch * HD * TLEN + (size_t)col * TLEN + tloc) = val;
    }
}

// ---------------- kernel 2: flash causal attention (split-K or full) ----------------
// out[b,t,:] = softmax_s( k[t]*q[s]/8, s<=t ) @ v   (Q-role := k, K-role := q)
// No max-subtraction: scores are bounded (|s*log2e/8| << 100), exp2/fp32 safe.
template<int SPLIT>
__global__ __launch_bounds__(256) void attn_kern(const short* __restrict__ kb,
                                                 const short* __restrict__ qb,
                                                 const short* __restrict__ vtw,
                                                 float* __restrict__ dst,  // SPLIT: pO ; else out
                                                 float* __restrict__ pL) { // SPLIT only
    __shared__ short Ks[64 * LDK];
    __shared__ short Vt[64 * LDK];
    __shared__ short Ps[64 * LDK];

    int tid = threadIdx.x;
    int wave = tid >> 6, lane = tid & 63;
    int quad = lane >> 4, l16 = lane & 15;
    int batch = blockIdx.y;

    int tile, j0, j1, slot = 0;
    if (SPLIT) {
        int bx = blockIdx.x;
        int t = 0, accb = 0;
        for (;;) { int p = (t + 8) >> 3; if (bx < accb + p) break; accb += p; ++t; }
        tile = t;
        int part = bx - accb;
        j0 = part * 8;
        int je = j0 + 8, lim = tile + 1;
        j1 = je < lim ? je : lim;
        slot = batch * PPB + bx;
    } else {
        tile = 63 - blockIdx.x;   // heavy tiles first
        j0 = 0; j1 = tile + 1;
    }
    int t0 = tile * 64;
    size_t base = (size_t)batch * TLEN * HD;
    const short* vbase = vtw + (size_t)batch * HD * TLEN;

    short8 qf[2];
    {
        int trow = t0 + wave * 16 + l16;
#pragma unroll
        for (int ks = 0; ks < 2; ks++)
            qf[ks] = *reinterpret_cast<const short8*>(kb + base + (size_t)trow * HD + ks * 32 + quad * 8);
    }

    floatx4 o_acc[4];
#pragma unroll
    for (int ht = 0; ht < 4; ht++) o_acc[ht] = (floatx4){0.f, 0.f, 0.f, 0.f};
    float l_sum[4] = {0.f, 0.f, 0.f, 0.f};
    const float sl2e = 0.18033688011112042f;  // (1/sqrt(64)) * log2(e)

    for (int j = j0; j < j1; ++j) {
        int s0 = j * 64;
        // stage K-role tile [s][h] (vector copies)
#pragma unroll
        for (int it = 0; it < 2; it++) {
            int i = tid + it * 256;
            int r = i >> 3, c = i & 7;
            *reinterpret_cast<int4*>(&Ks[r * LDK + c * 8]) =
                *reinterpret_cast<const int4*>(qb + base + (size_t)(s0 + r) * HD + c * 8);
        }
        // stage V^T tile [h][s] (pre-transposed in ws -> vector copies)
#pragma unroll
        for (int it = 0; it < 2; it++) {
            int i = tid + it * 256;
            int h = i >> 3, c = i & 7;
            *reinterpret_cast<int4*>(&Vt[h * LDK + c * 8]) =
                *reinterpret_cast<const int4*>(vbase + (size_t)h * TLEN + s0 + c * 8);
        }
        __syncthreads();

        floatx4 sacc[4];
#pragma unroll
        for (int nt = 0; nt < 4; nt++) sacc[nt] = (floatx4){0.f, 0.f, 0.f, 0.f};
#pragma unroll
        for (int ks = 0; ks < 2; ks++)
#pragma unroll
            for (int nt = 0; nt < 4; nt++) {
                short8 b = *reinterpret_cast<const short8*>(&Ks[(nt * 16 + l16) * LDK + ks * 32 + quad * 8]);
                sacc[nt] = __builtin_amdgcn_mfma_f32_16x16x32_bf16(qf[ks], b, sacc[nt], 0, 0, 0);
            }

        bool diag = (j == tile);
        float pv[4][4];
#pragma unroll
        for (int nt = 0; nt < 4; nt++) {
            int s_g = s0 + nt * 16 + l16;
#pragma unroll
            for (int reg = 0; reg < 4; reg++) {
                float p = __builtin_amdgcn_exp2f(sacc[nt][reg] * sl2e);
                if (diag && s_g > t0 + wave * 16 + quad * 4 + reg) p = 0.f;
                pv[nt][reg] = p;
            }
        }
#pragma unroll
        for (int reg = 0; reg < 4; reg++) {
            float s = (pv[0][reg] + pv[1][reg]) + (pv[2][reg] + pv[3][reg]);
#pragma unroll
            for (int off = 8; off >= 1; off >>= 1) s += __shfl_xor(s, off, 16);
            l_sum[reg] += s;
        }
        // P (C-layout) -> LDS A-layout; region is wave-private, no barrier needed
#pragma unroll
        for (int nt = 0; nt < 4; nt++)
#pragma unroll
            for (int reg = 0; reg < 4; reg++)
                Ps[(wave * 16 + quad * 4 + reg) * LDK + nt * 16 + l16] = f2bf(pv[nt][reg]);

#pragma unroll
        for (int ks = 0; ks < 2; ks++) {
            short8 a = *reinterpret_cast<const short8*>(&Ps[(wave * 16 + l16) * LDK + ks * 32 + quad * 8]);
#pragma unroll
            for (int ht = 0; ht < 4; ht++) {
                short8 b = *reinterpret_cast<const short8*>(&Vt[(ht * 16 + l16) * LDK + ks * 32 + quad * 8]);
                o_acc[ht] = __builtin_amdgcn_mfma_f32_16x16x32_bf16(a, b, o_acc[ht], 0, 0, 0);
            }
        }
        __syncthreads();
    }

    if (SPLIT) {
        float* po = dst + (size_t)slot * 4096;
#pragma unroll
        for (int ht = 0; ht < 4; ht++)
#pragma unroll
            for (int reg = 0; reg < 4; reg++)
                po[(wave * 16 + quad * 4 + reg) * 64 + ht * 16 + l16] = o_acc[ht][reg];
#pragma unroll
        for (int reg = 0; reg < 4; reg++)
            if (l16 == reg) pL[slot * 64 + wave * 16 + quad * 4 + reg] = l_sum[reg];
    } else {
        float inv[4];
#pragma unroll
        for (int reg = 0; reg < 4; reg++) inv[reg] = 1.0f / l_sum[reg];
#pragma unroll
        for (int ht = 0; ht < 4; ht++)
#pragma unroll
            for (int reg = 0; reg < 4; reg++)
                dst[base + (size_t)(t0 + wave * 16 + quad * 4 + reg) * HD + ht * 16 + l16] =
                    o_acc[ht][reg] * inv[reg];
    }
}

// ---------------- kernel 3: combine split-K partials ----------------
__global__ __launch_bounds__(256) void attn_combine(const float* __restrict__ pO,
                                                    const float* __restrict__ pL,
                                                    float* __restrict__ out) {
    int tile = blockIdx.x, batch = blockIdx.y;
    int nparts = (tile + 8) >> 3;
    int g = tile >> 3, r = tile & 7;
    int slot0 = batch * PPB + 4 * g * (g + 1) + r * (g + 1);
    int tid = threadIdx.x;
    int row = tid & 63, cg = tid >> 6;

    float L = 0.f;
    float4 acc[4];
#pragma unroll
    for (int i = 0; i < 4; i++) acc[i] = (float4){0.f, 0.f, 0.f, 0.f};

    for (int p = 0; p < nparts; ++p) {
        int slot = slot0 + p;
        L += pL[(size_t)slot * 64 + row];
        const float4* src = reinterpret_cast<const float4*>(pO + (size_t)slot * 4096 + row * 64 + cg * 16);
#pragma unroll
        for (int i = 0; i < 4; i++) {
            float4 v = src[i];
            acc[i].x += v.x; acc[i].y += v.y; acc[i].z += v.z; acc[i].w += v.w;
        }
    }
    float inv = 1.0f / L;
    float4* dstp = reinterpret_cast<float4*>(out + (size_t)batch * TLEN * HD +
                                             (size_t)(tile * 64 + row) * HD + cg * 16);
#pragma unroll
    for (int i = 0; i < 4; i++) {
        float4 v; v.x = acc[i].x * inv; v.y = acc[i].y * inv; v.z = acc[i].z * inv; v.w = acc[i].w * inv;
        dstp[i] = v;
    }
}

extern "C" void kernel_launch(void* const* d_in, const int* in_sizes, int n_in,
                              void* d_out, int out_size, void* d_ws, size_t ws_size,
                              hipStream_t stream) {
    const float* x  = (const float*)d_in[0];
    const float* Wk = (const float*)d_in[1];
    const float* bk = (const float*)d_in[2];
    const float* Wq = (const float*)d_in[3];
    const float* bq = (const float*)d_in[4];
    const float* Wv = (const float*)d_in[5];
    const float* bv = (const float*)d_in[6];
    float* out = (float*)d_out;

    const size_t nrow = (size_t)NB * TLEN;            // 16384
    short* ko = (short*)d_ws;                         // bf16 k [16384,64]        2 MB
    short* qo = ko + nrow * HD;                       // bf16 q                   2 MB
    short* vt = qo + nrow * HD;                       // bf16 v^T [4][64][4096]   2 MB
    short* wt = vt + nrow * HD;                       // bf16 W^T [3][64][1024]   384 KB
    float* pO = (float*)(wt + 3 * 64 * 1024);         // partial O [4*288][64][64]
    float* pL = pO + (size_t)NB * PPB * 4096;         // partial l [4*288][64]
    size_t need = (size_t)((char*)(pL + (size_t)NB * PPB * 64) - (char*)d_ws);

    prep_w<<<768, 256, 0, stream>>>(Wk, Wq, Wv, wt);
    proj<<<512, 256, 0, stream>>>(x, bk, bq, bv, wt, ko, qo, vt);
    if (ws_size >= need) {
        attn_kern<1><<<dim3(PPB, NB), 256, 0, stream>>>(ko, qo, vt, pO, pL);
        attn_combine<<<dim3(64, NB), 256, 0, stream>>>(pO, pL, out);
    } else {
        attn_kern<0><<<dim3(64, NB), 256, 0, stream>>>(ko, qo, vt, out, nullptr);
    }
}

// Round 3
// 164.354 us; speedup vs baseline: 1.5436x; 1.2381x over previous
//
#include <hip/hip_runtime.h>
#include <hip/hip_bf16.h>
#include <stdint.h>

typedef __attribute__((ext_vector_type(8))) short short8;
typedef __attribute__((ext_vector_type(4))) float floatx4;

#define HD 64
#define D_IN 1024
#define TLEN 4096
#define NB 4
#define PPB 288    // split-attn partial slots per batch: sum_{t=0}^{63} ceil((t+1)/8)
#define LDP 72     // padded stride for P buffer (bf16 elems)

__device__ __forceinline__ short f2bf(float f) {
    union { float f; uint32_t u; } v{f};
    uint32_t u = v.u;
    uint32_t r = (u + 0x7FFFu + ((u >> 16) & 1u)) >> 16;
    return (short)r;
}

__device__ __forceinline__ uint32_t pk2(float a, float b) {
    __hip_bfloat162 h = __float22bfloat162_rn(float2{a, b});
    union { __hip_bfloat162 h; uint32_t u; } c{h};
    return c.u;
}

// async 16-B global->LDS copy (fire-and-forget, no VGPR round trip)
__device__ __forceinline__ void ld_lds16(const void* g, void* l) {
    __builtin_amdgcn_global_load_lds(
        (const __attribute__((address_space(1))) uint32_t*)g,
        (__attribute__((address_space(3))) uint32_t*)l, 16, 0, 0);
}

// ---------------- kernel 0: W -> fragment-major bf16 wt in ws ----------------
// layout: [kt][f=mat*4+nt][ks][lane][j]  (16-B frag per lane, contiguous 1KB/frag)
// frag element: lane l holds W[k][n], n = nt*16 + (l&15), k = kt*64 + ks*32 + (l>>4)*8 + j
__global__ __launch_bounds__(256) void prep_w(const float* __restrict__ Wk,
                                              const float* __restrict__ Wq,
                                              const float* __restrict__ Wv,
                                              short* __restrict__ wt) {
    int i = blockIdx.x * 256 + threadIdx.x;      // 16*12*2*64*8 = 196608
    int j  = i & 7;
    int l  = (i >> 3) & 63;
    int ks = (i >> 9) & 1;
    int rest = i >> 10;            // kt*12 + f
    int f  = rest % 12;
    int kt = rest / 12;
    int mat = f >> 2, nt = f & 3;
    int n = nt * 16 + (l & 15);
    int k = kt * 64 + ks * 32 + (l >> 4) * 8 + j;
    const float* W = (mat == 0) ? Wk : ((mat == 1) ? Wq : Wv);
    wt[i] = f2bf(W[(size_t)k * 64 + n]);
}

// ---------------- kernel 1: fused QKV projection (m97-style) ----------------
// 64 rows/block, N=192 (12 frag-cols) split 3 per wave. Double-buffered LDS,
// all staging via global_load_lds. x staged fp32 with XOR-8 granule swizzle.
__global__ __launch_bounds__(256) void proj(const float* __restrict__ x,
                                            const float* __restrict__ bk,
                                            const float* __restrict__ bq,
                                            const float* __restrict__ bv,
                                            const short* __restrict__ wt,
                                            short* __restrict__ ko,
                                            short* __restrict__ qo,
                                            short* __restrict__ vt) {
    __shared__ float xs[2][4096];     // 16 KB per buf: 64 rows x 64 k fp32, swizzled
    __shared__ short ws2[2][12288];   // 24 KB per buf: 24 frags x 64 lanes x 16 B

    int tid = threadIdx.x;
    int wave = tid >> 6, lane = tid & 63;
    int quad = lane >> 4, l16 = lane & 15;
    int row0 = blockIdx.x * 64;
    int wbase = tid & ~63;            // wave-uniform slot base

    floatx4 acc[4][3];
#pragma unroll
    for (int mt = 0; mt < 4; mt++)
#pragma unroll
        for (int fi = 0; fi < 3; fi++) acc[mt][fi] = (floatx4){0.f, 0.f, 0.f, 0.f};

    auto stage = [&](int kt, int buf) {
        // x tile: 1024 16-B chunks; lane picks swizzled global chunk
#pragma unroll
        for (int it = 0; it < 4; it++) {
            int s = it * 256 + tid;
            int r = s >> 4, p = s & 15;
            int c = (((p >> 1) ^ (r & 7)) << 1) | (p & 1);
            ld_lds16(x + (size_t)(row0 + r) * D_IN + kt * 64 + c * 4,
                     &xs[buf][(it * 256 + wbase) * 4]);
        }
        // wt tile: contiguous fragment-major copy, 1536 chunks
#pragma unroll
        for (int it = 0; it < 6; it++) {
            int s = it * 256 + tid;
            ld_lds16(wt + (size_t)kt * 12288 + (size_t)s * 8,
                     &ws2[buf][(it * 256 + wbase) * 8]);
        }
    };

    stage(0, 0);
    for (int kt = 0; kt < 16; kt++) {
        int buf = kt & 1;
        __syncthreads();               // drains this iter's staging (issued last iter)
        if (kt < 15) stage(kt + 1, buf ^ 1);
#pragma unroll
        for (int ks = 0; ks < 2; ks++) {
            short8 av[4];
#pragma unroll
            for (int mt = 0; mt < 4; mt++) {
                int r = mt * 16 + l16;
                int g = ks * 4 + quad;
                const float4* pp = reinterpret_cast<const float4*>(
                    &xs[buf][r * 64 + ((g ^ (r & 7)) << 1) * 4]);
                float4 f0 = pp[0], f1 = pp[1];
                union { uint32_t u[4]; short8 s; } cv;
                cv.u[0] = pk2(f0.x, f0.y); cv.u[1] = pk2(f0.z, f0.w);
                cv.u[2] = pk2(f1.x, f1.y); cv.u[3] = pk2(f1.z, f1.w);
                av[mt] = cv.s;
            }
#pragma unroll
            for (int fi = 0; fi < 3; fi++) {
                int f = wave * 3 + fi;
                short8 bf = *reinterpret_cast<const short8*>(
                    &ws2[buf][((f * 2 + ks) * 64 + lane) * 8]);
#pragma unroll
                for (int mt = 0; mt < 4; mt++)
                    acc[mt][fi] = __builtin_amdgcn_mfma_f32_16x16x32_bf16(av[mt], bf, acc[mt][fi], 0, 0, 0);
            }
        }
    }

#pragma unroll
    for (int fi = 0; fi < 3; fi++) {
        int f = wave * 3 + fi;
        int mat = f >> 2, nt = f & 3;
        int col = nt * 16 + l16;
        const float* bias = (mat == 0) ? bk : ((mat == 1) ? bq : bv);
        float bb = bias[col];
#pragma unroll
        for (int mt = 0; mt < 4; mt++)
#pragma unroll
            for (int reg = 0; reg < 4; reg++) {
                float v = acc[mt][fi][reg] + bb;
                int row = row0 + mt * 16 + quad * 4 + reg;
                if (mat == 0) ko[(size_t)row * HD + col] = f2bf(v);
                else if (mat == 1) qo[(size_t)row * HD + col] = f2bf(v);
                else {
                    int bt = row >> 12, tl = row & 4095;
                    vt[(size_t)bt * HD * TLEN + (size_t)col * TLEN + tl] = f2bf(v);
                }
            }
    }
}

// ---------------- kernel 2: flash causal attention (split-K or full) ----------------
// out[b,t,:] = softmax_s( k[t].q[s]/8, s<=t ) @ v   (Q-role := k, K-role := q)
// No max-subtraction (scores bounded, exp2/fp32-safe). Double-buffered async staging.
template<int SPLIT>
__global__ __launch_bounds__(256) void attn_kern(const short* __restrict__ kb,
                                                 const short* __restrict__ qb,
                                                 const short* __restrict__ vtw,
                                                 float* __restrict__ dst,
                                                 float* __restrict__ pL) {
    __shared__ short Ks[2][4096];   // 8 KB/buf: 64 s-rows x 64 h, swizzled
    __shared__ short Vs[2][4096];   // 8 KB/buf: 64 h-rows x 64 s, swizzled
    __shared__ short Ps[64 * LDP];

    int tid = threadIdx.x;
    int wave = tid >> 6, lane = tid & 63;
    int quad = lane >> 4, l16 = lane & 15;
    int wbase = tid & ~63;
    int batch = blockIdx.y;

    int tile, j0, j1, slot = 0;
    if (SPLIT) {
        int bx = blockIdx.x;
        int t = 0, accb = 0;
        for (;;) { int p = (t + 8) >> 3; if (bx < accb + p) break; accb += p; ++t; }
        tile = t;
        j0 = (bx - accb) * 8;
        int je = j0 + 8, lim = tile + 1;
        j1 = je < lim ? je : lim;
        slot = batch * PPB + bx;
    } else {
        tile = 63 - blockIdx.x;
        j0 = 0; j1 = tile + 1;
    }
    int t0 = tile * 64;
    size_t base = (size_t)batch * TLEN * HD;
    const short* vbase = vtw + (size_t)batch * HD * TLEN;

    short8 qf[2];
    {
        int trow = t0 + wave * 16 + l16;
#pragma unroll
        for (int ks = 0; ks < 2; ks++)
            qf[ks] = *reinterpret_cast<const short8*>(kb + base + (size_t)trow * HD + ks * 32 + quad * 8);
    }

    floatx4 o_acc[4];
#pragma unroll
    for (int ht = 0; ht < 4; ht++) o_acc[ht] = (floatx4){0.f, 0.f, 0.f, 0.f};
    float l_sum[4] = {0.f, 0.f, 0.f, 0.f};
    const float sl2e = 0.18033688011112042f;  // (1/sqrt(64)) * log2(e)

    auto stage = [&](int j, int buf) {
        int s0 = j * 64;
#pragma unroll
        for (int it = 0; it < 2; it++) {
            int s = it * 256 + tid;
            int r = s >> 3, c = (s & 7) ^ (r & 7);
            ld_lds16(qb + base + (size_t)(s0 + r) * HD + c * 8,
                     &Ks[buf][(it * 256 + wbase) * 8]);
            ld_lds16(vbase + (size_t)r * TLEN + s0 + c * 8,
                     &Vs[buf][(it * 256 + wbase) * 8]);
        }
    };

    stage(j0, 0);
    for (int j = j0; j < j1; ++j) {
        int buf = (j - j0) & 1;
        __syncthreads();
        if (j + 1 < j1) stage(j + 1, buf ^ 1);

        int s0 = j * 64;
        floatx4 sacc[4];
#pragma unroll
        for (int nt = 0; nt < 4; nt++) sacc[nt] = (floatx4){0.f, 0.f, 0.f, 0.f};
#pragma unroll
        for (int ks = 0; ks < 2; ks++)
#pragma unroll
            for (int nt = 0; nt < 4; nt++) {
                int r = nt * 16 + l16, g = ks * 4 + quad;
                short8 b = *reinterpret_cast<const short8*>(
                    &Ks[buf][r * 64 + (g ^ (r & 7)) * 8]);
                sacc[nt] = __builtin_amdgcn_mfma_f32_16x16x32_bf16(qf[ks], b, sacc[nt], 0, 0, 0);
            }

        bool diag = (j == tile);
        float pv[4][4];
#pragma unroll
        for (int nt = 0; nt < 4; nt++) {
            int s_g = s0 + nt * 16 + l16;
#pragma unroll
            for (int reg = 0; reg < 4; reg++) {
                float p = __builtin_amdgcn_exp2f(sacc[nt][reg] * sl2e);
                if (diag && s_g > t0 + wave * 16 + quad * 4 + reg) p = 0.f;
                pv[nt][reg] = p;
            }
        }
#pragma unroll
        for (int reg = 0; reg < 4; reg++) {
            float s = (pv[0][reg] + pv[1][reg]) + (pv[2][reg] + pv[3][reg]);
#pragma unroll
            for (int off = 8; off >= 1; off >>= 1) s += __shfl_xor(s, off, 16);
            l_sum[reg] += s;
        }
        // P (C-layout) -> LDS A-layout; wave-private rows, no barrier needed
#pragma unroll
        for (int nt = 0; nt < 4; nt++)
#pragma unroll
            for (int reg = 0; reg < 4; reg++)
                Ps[(wave * 16 + quad * 4 + reg) * LDP + nt * 16 + l16] = f2bf(pv[nt][reg]);

#pragma unroll
        for (int ks = 0; ks < 2; ks++) {
            short8 a = *reinterpret_cast<const short8*>(&Ps[(wave * 16 + l16) * LDP + ks * 32 + quad * 8]);
#pragma unroll
            for (int ht = 0; ht < 4; ht++) {
                int r = ht * 16 + l16, g = ks * 4 + quad;
                short8 b = *reinterpret_cast<const short8*>(
                    &Vs[buf][r * 64 + (g ^ (r & 7)) * 8]);
                o_acc[ht] = __builtin_amdgcn_mfma_f32_16x16x32_bf16(a, b, o_acc[ht], 0, 0, 0);
            }
        }
    }

    if (SPLIT) {
        float* po = dst + (size_t)slot * 4096;
#pragma unroll
        for (int ht = 0; ht < 4; ht++)
#pragma unroll
            for (int reg = 0; reg < 4; reg++)
                po[(wave * 16 + quad * 4 + reg) * 64 + ht * 16 + l16] = o_acc[ht][reg];
#pragma unroll
        for (int reg = 0; reg < 4; reg++)
            if (l16 == reg) pL[(size_t)slot * 64 + wave * 16 + quad * 4 + reg] = l_sum[reg];
    } else {
        float inv[4];
#pragma unroll
        for (int reg = 0; reg < 4; reg++) inv[reg] = 1.0f / l_sum[reg];
#pragma unroll
        for (int ht = 0; ht < 4; ht++)
#pragma unroll
            for (int reg = 0; reg < 4; reg++)
                dst[base + (size_t)(t0 + wave * 16 + quad * 4 + reg) * HD + ht * 16 + l16] =
                    o_acc[ht][reg] * inv[reg];
    }
}

// ---------------- kernel 3: combine split-K partials (coalesced) ----------------
__global__ __launch_bounds__(256) void attn_combine(const float* __restrict__ pO,
                                                    const float* __restrict__ pL,
                                                    float* __restrict__ out) {
    int tile = blockIdx.x, batch = blockIdx.y;
    int nparts = (tile + 8) >> 3;
    int g = tile >> 3, r = tile & 7;
    int slot0 = batch * PPB + 4 * g * (g + 1) + r * (g + 1);
    int t = threadIdx.x;
    int row = t >> 2;                 // thread owns 64 contiguous bytes x 4

    float L = 0.f;
    float4 acc[4];
#pragma unroll
    for (int i = 0; i < 4; i++) acc[i] = (float4){0.f, 0.f, 0.f, 0.f};

    for (int p = 0; p < nparts; ++p) {
        int slot = slot0 + p;
        L += pL[(size_t)slot * 64 + row];
        const float4* src = reinterpret_cast<const float4*>(pO + (size_t)slot * 4096 + (size_t)t * 16);
#pragma unroll
        for (int i = 0; i < 4; i++) {
            float4 v = src[i];
            acc[i].x += v.x; acc[i].y += v.y; acc[i].z += v.z; acc[i].w += v.w;
        }
    }
    float inv = 1.0f / L;
    float4* dstp = reinterpret_cast<float4*>(out + (size_t)batch * TLEN * HD +
                                             (size_t)tile * 64 * HD + (size_t)t * 16);
#pragma unroll
    for (int i = 0; i < 4; i++) {
        float4 v; v.x = acc[i].x * inv; v.y = acc[i].y * inv; v.z = acc[i].z * inv; v.w = acc[i].w * inv;
        dstp[i] = v;
    }
}

extern "C" void kernel_launch(void* const* d_in, const int* in_sizes, int n_in,
                              void* d_out, int out_size, void* d_ws, size_t ws_size,
                              hipStream_t stream) {
    const float* x  = (const float*)d_in[0];
    const float* Wk = (const float*)d_in[1];
    const float* bk = (const float*)d_in[2];
    const float* Wq = (const float*)d_in[3];
    const float* bq = (const float*)d_in[4];
    const float* Wv = (const float*)d_in[5];
    const float* bv = (const float*)d_in[6];
    float* out = (float*)d_out;

    const size_t nrow = (size_t)NB * TLEN;            // 16384
    short* ko = (short*)d_ws;                         // bf16 k [16384,64]        2 MB
    short* qo = ko + nrow * HD;                       // bf16 q                   2 MB
    short* vt = qo + nrow * HD;                       // bf16 v^T [4][64][4096]   2 MB
    short* wt = vt + nrow * HD;                       // bf16 wt frag-major       384 KB
    float* pO = (float*)(wt + 3 * 64 * 1024);         // partial O
    float* pL = pO + (size_t)NB * PPB * 4096;         // partial l
    size_t need = (size_t)((char*)(pL + (size_t)NB * PPB * 64) - (char*)d_ws);

    prep_w<<<768, 256, 0, stream>>>(Wk, Wq, Wv, wt);
    proj<<<256, 256, 0, stream>>>(x, bk, bq, bv, wt, ko, qo, vt);
    if (ws_size >= need) {
        attn_kern<1><<<dim3(PPB, NB), 256, 0, stream>>>(ko, qo, vt, pO, pL);
        attn_combine<<<dim3(64, NB), 256, 0, stream>>>(pO, pL, out);
    } else {
        attn_kern<0><<<dim3(64, NB), 256, 0, stream>>>(ko, qo, vt, out, nullptr);
    }
}

// Round 4
// 160.583 us; speedup vs baseline: 1.5799x; 1.0235x over previous
//
#include <hip/hip_runtime.h>
#include <hip/hip_bf16.h>
#include <stdint.h>

typedef __attribute__((ext_vector_type(8))) short short8;
typedef __attribute__((ext_vector_type(4))) float floatx4;

#define HD 64
#define D_IN 1024
#define TLEN 4096
#define NB 4
#define PPB 144    // M=128 t-tiles: sum_{t=0}^{31} ceil((2t+2)/8)
#define LDP 72     // padded stride for P buffer (bf16 elems), 144 B (16B-aligned)
#define SL2E 0.18033688011112042f   // (1/sqrt(64)) * log2(e), folded into k

__device__ __forceinline__ short f2bf(float f) {
    union { float f; uint32_t u; } v{f};
    uint32_t u = v.u;
    uint32_t r = (u + 0x7FFFu + ((u >> 16) & 1u)) >> 16;
    return (short)r;
}

__device__ __forceinline__ uint32_t pk2(float a, float b) {
    __hip_bfloat162 h = __float22bfloat162_rn(float2{a, b});
    union { __hip_bfloat162 h; uint32_t u; } c{h};
    return c.u;
}

// async 16-B global->LDS copy (fire-and-forget, no VGPR round trip)
__device__ __forceinline__ void ld_lds16(const void* g, void* l) {
    __builtin_amdgcn_global_load_lds(
        (const __attribute__((address_space(1))) uint32_t*)g,
        (__attribute__((address_space(3))) uint32_t*)l, 16, 0, 0);
}

// ---------------- kernel 0: W -> fragment-major bf16 wt in ws ----------------
// layout: [kt][f=mat*4+nt][ks][lane][j]; lane l holds W[k][n],
// n = nt*16 + (l&15), k = kt*64 + ks*32 + (l>>4)*8 + j
__global__ __launch_bounds__(256) void prep_w(const float* __restrict__ Wk,
                                              const float* __restrict__ Wq,
                                              const float* __restrict__ Wv,
                                              short* __restrict__ wt) {
    int i = blockIdx.x * 256 + threadIdx.x;      // 196608
    int j  = i & 7;
    int l  = (i >> 3) & 63;
    int ks = (i >> 9) & 1;
    int rest = i >> 10;
    int f  = rest % 12;
    int kt = rest / 12;
    int mat = f >> 2, nt = f & 3;
    int n = nt * 16 + (l & 15);
    int k = kt * 64 + ks * 32 + (l >> 4) * 8 + j;
    const float* W = (mat == 0) ? Wk : ((mat == 1) ? Wq : Wv);
    wt[i] = f2bf(W[(size_t)k * 64 + n]);
}

// ---------------- kernel 1: fused QKV projection ----------------
// 32 rows/block (512 blocks -> 2 blocks/CU), double-buffered global_load_lds.
// k is pre-scaled by SL2E. v stored transposed vt[b][h][t].
__global__ __launch_bounds__(256) void proj(const float* __restrict__ x,
                                            const float* __restrict__ bk,
                                            const float* __restrict__ bq,
                                            const float* __restrict__ bv,
                                            const short* __restrict__ wt,
                                            short* __restrict__ ko,
                                            short* __restrict__ qo,
                                            short* __restrict__ vt) {
    __shared__ float xs[2][2048];     // 8 KB/buf: 32 rows x 64 k fp32, swizzled
    __shared__ short ws2[2][12288];   // 24 KB/buf: 24 frags x 64 lanes x 16 B

    int tid = threadIdx.x;
    int wave = tid >> 6, lane = tid & 63;
    int quad = lane >> 4, l16 = lane & 15;
    int row0 = blockIdx.x * 32;
    int wbase = tid & ~63;

    floatx4 acc[2][3];
#pragma unroll
    for (int mt = 0; mt < 2; mt++)
#pragma unroll
        for (int fi = 0; fi < 3; fi++) acc[mt][fi] = (floatx4){0.f, 0.f, 0.f, 0.f};

    auto stage = [&](int kt, int buf) {
#pragma unroll
        for (int it = 0; it < 2; it++) {          // x: 512 chunks
            int s = it * 256 + tid;
            int r = s >> 4, p = s & 15;
            int c = (((p >> 1) ^ (r & 7)) << 1) | (p & 1);
            ld_lds16(x + (size_t)(row0 + r) * D_IN + kt * 64 + c * 4,
                     &xs[buf][(it * 256 + wbase) * 4]);
        }
#pragma unroll
        for (int it = 0; it < 6; it++) {          // wt: 1536 chunks, linear
            int s = it * 256 + tid;
            ld_lds16(wt + (size_t)kt * 12288 + (size_t)s * 8,
                     &ws2[buf][(it * 256 + wbase) * 8]);
        }
    };

    stage(0, 0);
    for (int kt = 0; kt < 16; kt++) {
        int buf = kt & 1;
        __syncthreads();
        if (kt < 15) stage(kt + 1, buf ^ 1);
#pragma unroll
        for (int ks = 0; ks < 2; ks++) {
            short8 av[2];
#pragma unroll
            for (int mt = 0; mt < 2; mt++) {
                int r = mt * 16 + l16;
                int g = ks * 4 + quad;
                const float4* pp = reinterpret_cast<const float4*>(
                    &xs[buf][r * 64 + ((g ^ (r & 7)) << 1) * 4]);
                float4 f0 = pp[0], f1 = pp[1];
                union { uint32_t u[4]; short8 s; } cv;
                cv.u[0] = pk2(f0.x, f0.y); cv.u[1] = pk2(f0.z, f0.w);
                cv.u[2] = pk2(f1.x, f1.y); cv.u[3] = pk2(f1.z, f1.w);
                av[mt] = cv.s;
            }
#pragma unroll
            for (int fi = 0; fi < 3; fi++) {
                int f = wave * 3 + fi;
                short8 bf = *reinterpret_cast<const short8*>(
                    &ws2[buf][((f * 2 + ks) * 64 + lane) * 8]);
#pragma unroll
                for (int mt = 0; mt < 2; mt++)
                    acc[mt][fi] = __builtin_amdgcn_mfma_f32_16x16x32_bf16(av[mt], bf, acc[mt][fi], 0, 0, 0);
            }
        }
    }

#pragma unroll
    for (int fi = 0; fi < 3; fi++) {
        int f = wave * 3 + fi;
        int mat = f >> 2, nt = f & 3;
        int col = nt * 16 + l16;
        const float* bias = (mat == 0) ? bk : ((mat == 1) ? bq : bv);
        float bb = bias[col];
#pragma unroll
        for (int mt = 0; mt < 2; mt++)
#pragma unroll
            for (int reg = 0; reg < 4; reg++) {
                float v = acc[mt][fi][reg] + bb;
                int row = row0 + mt * 16 + quad * 4 + reg;
                if (mat == 0) ko[(size_t)row * HD + col] = f2bf(v * SL2E);
                else if (mat == 1) qo[(size_t)row * HD + col] = f2bf(v);
                else {
                    int bt = row >> 12, tl = row & 4095;
                    vt[(size_t)bt * HD * TLEN + (size_t)col * TLEN + tl] = f2bf(v);
                }
            }
    }
}

// ---------------- kernel 2: flash causal attention, M=128, split-K ----------------
// out[b,t,:] = softmax_s( k[t].q[s] (k pre-scaled), s<=t ) @ v
// No max-subtraction; l-reduce deferred to the end (pure sum).
template<int SPLIT>
__global__ __launch_bounds__(256) void attn_kern(const short* __restrict__ kb,
                                                 const short* __restrict__ qb,
                                                 const short* __restrict__ vtw,
                                                 float* __restrict__ dst,
                                                 float* __restrict__ pL) {
    __shared__ short Ks[2][4096];   // 8 KB/buf: 64 s x 64 h, swizzled
    __shared__ short Vs[2][4096];   // 8 KB/buf: 64 h x 64 s, swizzled
    __shared__ short Ps[128 * LDP]; // 18.4 KB

    int tid = threadIdx.x;
    int wave = tid >> 6, lane = tid & 63;
    int quad = lane >> 4, l16 = lane & 15;
    int wbase = tid & ~63;
    int batch = blockIdx.y;

    int tile, j0, j1, slot = 0;
    if (SPLIT) {
        int bx = blockIdx.x;
        int t = 0, accb = 0;
        for (;;) { int p = (2 * t + 9) >> 3; if (bx < accb + p) break; accb += p; ++t; }
        tile = t;
        j0 = (bx - accb) * 8;
        int je = j0 + 8, lim = 2 * tile + 2;
        j1 = je < lim ? je : lim;
        slot = batch * PPB + bx;
    } else {
        tile = 31 - blockIdx.x;
        j0 = 0; j1 = 2 * tile + 2;
    }
    int t0 = tile * 128;
    int jd = 2 * tile;               // j >= jd needs causal masking
    size_t base = (size_t)batch * TLEN * HD;
    const short* vbase = vtw + (size_t)batch * HD * TLEN;

    short8 qf[2][2];                 // [mt][ks], rows = pre-scaled k vectors
#pragma unroll
    for (int mt = 0; mt < 2; mt++) {
        int trow = t0 + wave * 32 + mt * 16 + l16;
#pragma unroll
        for (int ks = 0; ks < 2; ks++)
            qf[mt][ks] = *reinterpret_cast<const short8*>(kb + base + (size_t)trow * HD + ks * 32 + quad * 8);
    }

    floatx4 o_acc[2][4];
#pragma unroll
    for (int mt = 0; mt < 2; mt++)
#pragma unroll
        for (int ht = 0; ht < 4; ht++) o_acc[mt][ht] = (floatx4){0.f, 0.f, 0.f, 0.f};
    float l_p[2][4] = {{0.f,0.f,0.f,0.f},{0.f,0.f,0.f,0.f}};

    auto stage = [&](int j, int buf) {
        int s0 = j * 64;
#pragma unroll
        for (int it = 0; it < 2; it++) {
            int s = it * 256 + tid;
            int r = s >> 3, c = (s & 7) ^ (r & 7);
            ld_lds16(qb + base + (size_t)(s0 + r) * HD + c * 8,
                     &Ks[buf][(it * 256 + wbase) * 8]);
            ld_lds16(vbase + (size_t)r * TLEN + s0 + c * 8,
                     &Vs[buf][(it * 256 + wbase) * 8]);
        }
    };

    stage(j0, 0);
    for (int j = j0; j < j1; ++j) {
        int buf = (j - j0) & 1;
        __syncthreads();
        if (j + 1 < j1) stage(j + 1, buf ^ 1);

        // S = qf x Ks^T : 16 MFMA, B-frags shared across mt
        floatx4 sacc[2][4];
#pragma unroll
        for (int mt = 0; mt < 2; mt++)
#pragma unroll
            for (int nt = 0; nt < 4; nt++) sacc[mt][nt] = (floatx4){0.f, 0.f, 0.f, 0.f};
#pragma unroll
        for (int ks = 0; ks < 2; ks++)
#pragma unroll
            for (int nt = 0; nt < 4; nt++) {
                int r = nt * 16 + l16, g = ks * 4 + quad;
                short8 b = *reinterpret_cast<const short8*>(
                    &Ks[buf][r * 64 + (g ^ (r & 7)) * 8]);
#pragma unroll
                for (int mt = 0; mt < 2; mt++)
                    sacc[mt][nt] = __builtin_amdgcn_mfma_f32_16x16x32_bf16(qf[mt][ks], b, sacc[mt][nt], 0, 0, 0);
            }

        // exp2 (k pre-scaled), causal mask only on the last two j-tiles
        float pv[2][4][4];
#pragma unroll
        for (int mt = 0; mt < 2; mt++)
#pragma unroll
            for (int nt = 0; nt < 4; nt++)
#pragma unroll
                for (int reg = 0; reg < 4; reg++)
                    pv[mt][nt][reg] = __builtin_amdgcn_exp2f(sacc[mt][nt][reg]);
        if (j >= jd) {
            int s0 = j * 64;
#pragma unroll
            for (int mt = 0; mt < 2; mt++) {
                int tg = t0 + wave * 32 + mt * 16 + quad * 4;
#pragma unroll
                for (int nt = 0; nt < 4; nt++) {
                    int s_g = s0 + nt * 16 + l16;
#pragma unroll
                    for (int reg = 0; reg < 4; reg++)
                        if (s_g > tg + reg) pv[mt][nt][reg] = 0.f;
                }
            }
        }
        // accumulate per-lane l partials (reduce deferred) + P -> LDS (A-layout)
#pragma unroll
        for (int mt = 0; mt < 2; mt++)
#pragma unroll
            for (int reg = 0; reg < 4; reg++)
                l_p[mt][reg] += (pv[mt][0][reg] + pv[mt][1][reg]) + (pv[mt][2][reg] + pv[mt][3][reg]);
#pragma unroll
        for (int mt = 0; mt < 2; mt++)
#pragma unroll
            for (int nt = 0; nt < 4; nt++)
#pragma unroll
                for (int reg = 0; reg < 4; reg++)
                    Ps[(wave * 32 + mt * 16 + quad * 4 + reg) * LDP + nt * 16 + l16] = f2bf(pv[mt][nt][reg]);

        // O += P @ V : 16 MFMA, B-frags shared across mt
#pragma unroll
        for (int ks = 0; ks < 2; ks++) {
            short8 a[2];
#pragma unroll
            for (int mt = 0; mt < 2; mt++)
                a[mt] = *reinterpret_cast<const short8*>(
                    &Ps[(wave * 32 + mt * 16 + l16) * LDP + ks * 32 + quad * 8]);
#pragma unroll
            for (int ht = 0; ht < 4; ht++) {
                int r = ht * 16 + l16, g = ks * 4 + quad;
                short8 b = *reinterpret_cast<const short8*>(
                    &Vs[buf][r * 64 + (g ^ (r & 7)) * 8]);
#pragma unroll
                for (int mt = 0; mt < 2; mt++)
                    o_acc[mt][ht] = __builtin_amdgcn_mfma_f32_16x16x32_bf16(a[mt], b, o_acc[mt][ht], 0, 0, 0);
            }
        }
    }

    // one-time l reduction within each quad (width 16 = one row group)
#pragma unroll
    for (int mt = 0; mt < 2; mt++)
#pragma unroll
        for (int reg = 0; reg < 4; reg++) {
            float s = l_p[mt][reg];
#pragma unroll
            for (int off = 8; off >= 1; off >>= 1) s += __shfl_xor(s, off, 16);
            l_p[mt][reg] = s;
        }

    if (SPLIT) {
        float* po = dst + (size_t)slot * 8192;
#pragma unroll
        for (int mt = 0; mt < 2; mt++)
#pragma unroll
            for (int ht = 0; ht < 4; ht++)
#pragma unroll
                for (int reg = 0; reg < 4; reg++) {
                    int lr = wave * 32 + mt * 16 + quad * 4 + reg;
                    po[lr * 64 + ht * 16 + l16] = o_acc[mt][ht][reg];
                }
#pragma unroll
        for (int mt = 0; mt < 2; mt++)
#pragma unroll
            for (int reg = 0; reg < 4; reg++)
                if (l16 == mt * 4 + reg)
                    pL[(size_t)slot * 128 + wave * 32 + mt * 16 + quad * 4 + reg] = l_p[mt][reg];
    } else {
#pragma unroll
        for (int mt = 0; mt < 2; mt++)
#pragma unroll
            for (int reg = 0; reg < 4; reg++) {
                float inv = 1.0f / l_p[mt][reg];
                int t = t0 + wave * 32 + mt * 16 + quad * 4 + reg;
#pragma unroll
                for (int ht = 0; ht < 4; ht++)
                    dst[base + (size_t)t * HD + ht * 16 + l16] = o_acc[mt][ht][reg] * inv;
            }
    }
}

// ---------------- kernel 3: combine split-K partials (coalesced) ----------------
__global__ __launch_bounds__(256) void attn_combine(const float* __restrict__ pO,
                                                    const float* __restrict__ pL,
                                                    float* __restrict__ out) {
    int tile = blockIdx.x, batch = blockIdx.y;
    int nparts = (2 * tile + 9) >> 3;
    int a = tile >> 2, r = tile & 3;
    int slot0 = batch * PPB + 2 * a * (a + 1) + r * (a + 1);
    int t = threadIdx.x;
    int off = t * 32;                 // thread owns 32 contiguous floats
    int row = off >> 6;

    float L = 0.f;
    float4 acc[8];
#pragma unroll
    for (int i = 0; i < 8; i++) acc[i] = (float4){0.f, 0.f, 0.f, 0.f};

    for (int p = 0; p < nparts; ++p) {
        int slot = slot0 + p;
        L += pL[(size_t)slot * 128 + row];
        const float4* src = reinterpret_cast<const float4*>(pO + (size_t)slot * 8192 + off);
#pragma unroll
        for (int i = 0; i < 8; i++) {
            float4 v = src[i];
            acc[i].x += v.x; acc[i].y += v.y; acc[i].z += v.z; acc[i].w += v.w;
        }
    }
    float inv = 1.0f / L;
    float4* dstp = reinterpret_cast<float4*>(out + (size_t)batch * TLEN * HD +
                                             (size_t)tile * 128 * HD + off);
#pragma unroll
    for (int i = 0; i < 8; i++) {
        float4 v; v.x = acc[i].x * inv; v.y = acc[i].y * inv; v.z = acc[i].z * inv; v.w = acc[i].w * inv;
        dstp[i] = v;
    }
}

extern "C" void kernel_launch(void* const* d_in, const int* in_sizes, int n_in,
                              void* d_out, int out_size, void* d_ws, size_t ws_size,
                              hipStream_t stream) {
    const float* x  = (const float*)d_in[0];
    const float* Wk = (const float*)d_in[1];
    const float* bk = (const float*)d_in[2];
    const float* Wq = (const float*)d_in[3];
    const float* bq = (const float*)d_in[4];
    const float* Wv = (const float*)d_in[5];
    const float* bv = (const float*)d_in[6];
    float* out = (float*)d_out;

    const size_t nrow = (size_t)NB * TLEN;            // 16384
    short* ko = (short*)d_ws;                         // bf16 k (pre-scaled)      2 MB
    short* qo = ko + nrow * HD;                       // bf16 q                   2 MB
    short* vt = qo + nrow * HD;                       // bf16 v^T [4][64][4096]   2 MB
    short* wt = vt + nrow * HD;                       // bf16 wt frag-major       384 KB
    float* pO = (float*)(wt + 3 * 64 * 1024);         // partial O [4*144][128][64]
    float* pL = pO + (size_t)NB * PPB * 8192;         // partial l [4*144][128]
    size_t need = (size_t)((char*)(pL + (size_t)NB * PPB * 128) - (char*)d_ws);

    prep_w<<<768, 256, 0, stream>>>(Wk, Wq, Wv, wt);
    proj<<<512, 256, 0, stream>>>(x, bk, bq, bv, wt, ko, qo, vt);
    if (ws_size >= need) {
        attn_kern<1><<<dim3(PPB, NB), 256, 0, stream>>>(ko, qo, vt, pO, pL);
        attn_combine<<<dim3(32, NB), 256, 0, stream>>>(pO, pL, out);
    } else {
        attn_kern<0><<<dim3(32, NB), 256, 0, stream>>>(ko, qo, vt, out, nullptr);
    }
}

// Round 5
// 156.397 us; speedup vs baseline: 1.6221x; 1.0268x over previous
//
#include <hip/hip_runtime.h>
#include <hip/hip_bf16.h>
#include <stdint.h>

typedef __attribute__((ext_vector_type(8))) short short8;
typedef __attribute__((ext_vector_type(4))) float floatx4;

#define HD 64
#define D_IN 1024
#define TLEN 4096
#define NB 4
#define PPB 144    // M=128 t-tiles: sum_{t=0}^{31} ceil((2t+2)/8)
#define LDP 72     // padded stride for P buffer (bf16 elems), 144 B (16B-aligned)
#define SL2E 0.18033688011112042f   // (1/sqrt(64)) * log2(e), folded into k

__device__ __forceinline__ short f2bf(float f) {
    union { float f; uint32_t u; } v{f};
    uint32_t u = v.u;
    uint32_t r = (u + 0x7FFFu + ((u >> 16) & 1u)) >> 16;
    return (short)r;
}

__device__ __forceinline__ uint32_t pk2(float a, float b) {
    __hip_bfloat162 h = __float22bfloat162_rn(float2{a, b});
    union { __hip_bfloat162 h; uint32_t u; } c{h};
    return c.u;
}

// async 16-B global->LDS copy (fire-and-forget, no VGPR round trip)
__device__ __forceinline__ void ld_lds16(const void* g, void* l) {
    __builtin_amdgcn_global_load_lds(
        (const __attribute__((address_space(1))) uint32_t*)g,
        (__attribute__((address_space(3))) uint32_t*)l, 16, 0, 0);
}

// ---------------- kernel 0: W -> fragment-major bf16 wt in ws ----------------
__global__ __launch_bounds__(256) void prep_w(const float* __restrict__ Wk,
                                              const float* __restrict__ Wq,
                                              const float* __restrict__ Wv,
                                              short* __restrict__ wt) {
    int i = blockIdx.x * 256 + threadIdx.x;      // 196608
    int j  = i & 7;
    int l  = (i >> 3) & 63;
    int ks = (i >> 9) & 1;
    int rest = i >> 10;
    int f  = rest % 12;
    int kt = rest / 12;
    int mat = f >> 2, nt = f & 3;
    int n = nt * 16 + (l & 15);
    int k = kt * 64 + ks * 32 + (l >> 4) * 8 + j;
    const float* W = (mat == 0) ? Wk : ((mat == 1) ? Wq : Wv);
    wt[i] = f2bf(W[(size_t)k * 64 + n]);
}

// ---------------- kernel 1: fused QKV projection ----------------
// 32 rows/block (512 blocks), double-buffered global_load_lds.
// k pre-scaled by SL2E. v stored transposed vt[b][h][t].
__global__ __launch_bounds__(256) void proj(const float* __restrict__ x,
                                            const float* __restrict__ bk,
                                            const float* __restrict__ bq,
                                            const float* __restrict__ bv,
                                            const short* __restrict__ wt,
                                            short* __restrict__ ko,
                                            short* __restrict__ qo,
                                            short* __restrict__ vt) {
    __shared__ float xs[2][2048];
    __shared__ short ws2[2][12288];

    int tid = threadIdx.x;
    int wave = tid >> 6, lane = tid & 63;
    int quad = lane >> 4, l16 = lane & 15;
    int row0 = blockIdx.x * 32;
    int wbase = tid & ~63;

    floatx4 acc[2][3];
#pragma unroll
    for (int mt = 0; mt < 2; mt++)
#pragma unroll
        for (int fi = 0; fi < 3; fi++) acc[mt][fi] = (floatx4){0.f, 0.f, 0.f, 0.f};

    auto stage = [&](int kt, int buf) {
#pragma unroll
        for (int it = 0; it < 2; it++) {
            int s = it * 256 + tid;
            int r = s >> 4, p = s & 15;
            int c = (((p >> 1) ^ (r & 7)) << 1) | (p & 1);
            ld_lds16(x + (size_t)(row0 + r) * D_IN + kt * 64 + c * 4,
                     &xs[buf][(it * 256 + wbase) * 4]);
        }
#pragma unroll
        for (int it = 0; it < 6; it++) {
            int s = it * 256 + tid;
            ld_lds16(wt + (size_t)kt * 12288 + (size_t)s * 8,
                     &ws2[buf][(it * 256 + wbase) * 8]);
        }
    };

    stage(0, 0);
    for (int kt = 0; kt < 16; kt++) {
        int buf = kt & 1;
        __syncthreads();
        if (kt < 15) stage(kt + 1, buf ^ 1);
#pragma unroll
        for (int ks = 0; ks < 2; ks++) {
            short8 av[2];
#pragma unroll
            for (int mt = 0; mt < 2; mt++) {
                int r = mt * 16 + l16;
                int g = ks * 4 + quad;
                const float4* pp = reinterpret_cast<const float4*>(
                    &xs[buf][r * 64 + ((g ^ (r & 7)) << 1) * 4]);
                float4 f0 = pp[0], f1 = pp[1];
                union { uint32_t u[4]; short8 s; } cv;
                cv.u[0] = pk2(f0.x, f0.y); cv.u[1] = pk2(f0.z, f0.w);
                cv.u[2] = pk2(f1.x, f1.y); cv.u[3] = pk2(f1.z, f1.w);
                av[mt] = cv.s;
            }
#pragma unroll
            for (int fi = 0; fi < 3; fi++) {
                int f = wave * 3 + fi;
                short8 bf = *reinterpret_cast<const short8*>(
                    &ws2[buf][((f * 2 + ks) * 64 + lane) * 8]);
#pragma unroll
                for (int mt = 0; mt < 2; mt++)
                    acc[mt][fi] = __builtin_amdgcn_mfma_f32_16x16x32_bf16(av[mt], bf, acc[mt][fi], 0, 0, 0);
            }
        }
    }

#pragma unroll
    for (int fi = 0; fi < 3; fi++) {
        int f = wave * 3 + fi;
        int mat = f >> 2, nt = f & 3;
        int col = nt * 16 + l16;
        const float* bias = (mat == 0) ? bk : ((mat == 1) ? bq : bv);
        float bb = bias[col];
#pragma unroll
        for (int mt = 0; mt < 2; mt++)
#pragma unroll
            for (int reg = 0; reg < 4; reg++) {
                float v = acc[mt][fi][reg] + bb;
                int row = row0 + mt * 16 + quad * 4 + reg;
                if (mat == 0) ko[(size_t)row * HD + col] = f2bf(v * SL2E);
                else if (mat == 1) qo[(size_t)row * HD + col] = f2bf(v);
                else {
                    int bt = row >> 12, tl = row & 4095;
                    vt[(size_t)bt * HD * TLEN + (size_t)col * TLEN + tl] = f2bf(v);
                }
            }
    }
}

// ---------------- kernel 2: flash causal attention, M=128, split-K ----------------
// Computes S^T (A := staged q rows from LDS, B := per-wave k fragments), so the
// P C-layout has t=l16 / s=quad*4+reg: packed b64 P-writes + cheap l handling.
template<int SPLIT>
__global__ __launch_bounds__(256) void attn_kern(const short* __restrict__ kb,
                                                 const short* __restrict__ qb,
                                                 const short* __restrict__ vtw,
                                                 float* __restrict__ dst,
                                                 float* __restrict__ pL) {
    __shared__ short Ks[2][4096];   // 8 KB/buf: 64 s x 64 h, swizzled
    __shared__ short Vs[2][4096];   // 8 KB/buf: 64 h x 64 s, swizzled
    __shared__ short Ps[128 * LDP]; // P^T staging in [t][s] row-major

    int tid = threadIdx.x;
    int wave = tid >> 6, lane = tid & 63;
    int quad = lane >> 4, l16 = lane & 15;
    int wbase = tid & ~63;
    int batch = blockIdx.y;

    int tile, j0, j1, slot = 0;
    if (SPLIT) {
        int bx = blockIdx.x;
        int t = 0, accb = 0;
        for (;;) { int p = (2 * t + 9) >> 3; if (bx < accb + p) break; accb += p; ++t; }
        tile = t;
        j0 = (bx - accb) * 8;
        int je = j0 + 8, lim = 2 * tile + 2;
        j1 = je < lim ? je : lim;
        slot = batch * PPB + bx;
    } else {
        tile = 31 - blockIdx.x;
        j0 = 0; j1 = 2 * tile + 2;
    }
    int t0 = tile * 128;
    int jd = 2 * tile;               // j >= jd needs causal masking
    size_t base = (size_t)batch * TLEN * HD;
    const short* vbase = vtw + (size_t)batch * HD * TLEN;

    // k-vectors as B-fragments (n = t = l16, k = h): same bytes as an A-frag load
    short8 kf[2][2];                 // [mt][ks]
#pragma unroll
    for (int mt = 0; mt < 2; mt++) {
        int trow = t0 + wave * 32 + mt * 16 + l16;
#pragma unroll
        for (int ks = 0; ks < 2; ks++)
            kf[mt][ks] = *reinterpret_cast<const short8*>(kb + base + (size_t)trow * HD + ks * 32 + quad * 8);
    }

    floatx4 o_acc[2][4];
#pragma unroll
    for (int mt = 0; mt < 2; mt++)
#pragma unroll
        for (int ht = 0; ht < 4; ht++) o_acc[mt][ht] = (floatx4){0.f, 0.f, 0.f, 0.f};
    float l_p[2] = {0.f, 0.f};       // per-lane partial of l(t = l16 of mt tile)

    auto stage = [&](int j, int buf) {
        int s0 = j * 64;
#pragma unroll
        for (int it = 0; it < 2; it++) {
            int s = it * 256 + tid;
            int r = s >> 3, c = (s & 7) ^ (r & 7);
            ld_lds16(qb + base + (size_t)(s0 + r) * HD + c * 8,
                     &Ks[buf][(it * 256 + wbase) * 8]);
            ld_lds16(vbase + (size_t)r * TLEN + s0 + c * 8,
                     &Vs[buf][(it * 256 + wbase) * 8]);
        }
    };

    stage(j0, 0);
    for (int j = j0; j < j1; ++j) {
        int buf = (j - j0) & 1;
        __syncthreads();
        if (j + 1 < j1) stage(j + 1, buf ^ 1);

        // S^T = Qs(A) x kf(B): C[m=s][n=t], 16 MFMA, A-frags shared across mt
        floatx4 sacc[2][4];
#pragma unroll
        for (int mt = 0; mt < 2; mt++)
#pragma unroll
            for (int nt = 0; nt < 4; nt++) sacc[mt][nt] = (floatx4){0.f, 0.f, 0.f, 0.f};
#pragma unroll
        for (int ks = 0; ks < 2; ks++)
#pragma unroll
            for (int nt = 0; nt < 4; nt++) {
                int r = nt * 16 + l16, g = ks * 4 + quad;
                short8 a = *reinterpret_cast<const short8*>(
                    &Ks[buf][r * 64 + (g ^ (r & 7)) * 8]);
#pragma unroll
                for (int mt = 0; mt < 2; mt++)
                    sacc[mt][nt] = __builtin_amdgcn_mfma_f32_16x16x32_bf16(a, kf[mt][ks], sacc[mt][nt], 0, 0, 0);
            }

        // exp2 (k pre-scaled); causal mask only on the last two j-tiles
        float pv[2][4][4];
#pragma unroll
        for (int mt = 0; mt < 2; mt++)
#pragma unroll
            for (int nt = 0; nt < 4; nt++)
#pragma unroll
                for (int reg = 0; reg < 4; reg++)
                    pv[mt][nt][reg] = __builtin_amdgcn_exp2f(sacc[mt][nt][reg]);
        if (j >= jd) {
            int s0 = j * 64;
#pragma unroll
            for (int mt = 0; mt < 2; mt++) {
                int t_g = t0 + wave * 32 + mt * 16 + l16;
#pragma unroll
                for (int nt = 0; nt < 4; nt++) {
                    int s_g = s0 + nt * 16 + quad * 4;
#pragma unroll
                    for (int reg = 0; reg < 4; reg++)
                        if (s_g + reg > t_g) pv[mt][nt][reg] = 0.f;
                }
            }
        }
        // l partials (t = l16, pure per-lane adds) + packed P^T -> LDS (b64 writes)
#pragma unroll
        for (int mt = 0; mt < 2; mt++) {
            l_p[mt] += ((pv[mt][0][0] + pv[mt][0][1]) + (pv[mt][0][2] + pv[mt][0][3]))
                     + ((pv[mt][1][0] + pv[mt][1][1]) + (pv[mt][1][2] + pv[mt][1][3]))
                     + ((pv[mt][2][0] + pv[mt][2][1]) + (pv[mt][2][2] + pv[mt][2][3]))
                     + ((pv[mt][3][0] + pv[mt][3][1]) + (pv[mt][3][2] + pv[mt][3][3]));
#pragma unroll
            for (int nt = 0; nt < 4; nt++) {
                union { uint32_t u[2]; uint64_t q; } w;
                w.u[0] = pk2(pv[mt][nt][0], pv[mt][nt][1]);
                w.u[1] = pk2(pv[mt][nt][2], pv[mt][nt][3]);
                int row = wave * 32 + mt * 16 + l16;
                *reinterpret_cast<uint64_t*>(&Ps[row * LDP + nt * 16 + quad * 4]) = w.q;
            }
        }

        // O += P @ V : A = P (m=t=l16, k=s contiguous), B = V^T
#pragma unroll
        for (int ks = 0; ks < 2; ks++) {
            short8 a[2];
#pragma unroll
            for (int mt = 0; mt < 2; mt++)
                a[mt] = *reinterpret_cast<const short8*>(
                    &Ps[(wave * 32 + mt * 16 + l16) * LDP + ks * 32 + quad * 8]);
#pragma unroll
            for (int ht = 0; ht < 4; ht++) {
                int r = ht * 16 + l16, g = ks * 4 + quad;
                short8 b = *reinterpret_cast<const short8*>(
                    &Vs[buf][r * 64 + (g ^ (r & 7)) * 8]);
#pragma unroll
                for (int mt = 0; mt < 2; mt++)
                    o_acc[mt][ht] = __builtin_amdgcn_mfma_f32_16x16x32_bf16(a[mt], b, o_acc[mt][ht], 0, 0, 0);
            }
        }
    }

    // final l reduction across quads: every lane ends with L(t = l16 of its mt tile)
#pragma unroll
    for (int mt = 0; mt < 2; mt++) {
        l_p[mt] += __shfl_xor(l_p[mt], 16);
        l_p[mt] += __shfl_xor(l_p[mt], 32);
    }

    if (SPLIT) {
        float* po = dst + (size_t)slot * 8192;
#pragma unroll
        for (int mt = 0; mt < 2; mt++)
#pragma unroll
            for (int ht = 0; ht < 4; ht++)
#pragma unroll
                for (int reg = 0; reg < 4; reg++) {
                    int lr = wave * 32 + mt * 16 + quad * 4 + reg;
                    po[lr * 64 + ht * 16 + l16] = o_acc[mt][ht][reg];
                }
        if (quad == 0) {
#pragma unroll
            for (int mt = 0; mt < 2; mt++)
                pL[(size_t)slot * 128 + wave * 32 + mt * 16 + l16] = l_p[mt];
        }
    } else {
#pragma unroll
        for (int mt = 0; mt < 2; mt++) {
            // move L to the o_acc row layout: row t_loc = quad*4+reg needs L from lane l16=t_loc
#pragma unroll
            for (int reg = 0; reg < 4; reg++) {
                float L = __shfl(l_p[mt], quad * 4 + reg, 64);
                float inv = 1.0f / L;
                int t = t0 + wave * 32 + mt * 16 + quad * 4 + reg;
#pragma unroll
                for (int ht = 0; ht < 4; ht++)
                    dst[base + (size_t)t * HD + ht * 16 + l16] = o_acc[mt][ht][reg] * inv;
            }
        }
    }
}

// ---------------- kernel 3: combine split-K partials (coalesced) ----------------
__global__ __launch_bounds__(256) void attn_combine(const float* __restrict__ pO,
                                                    const float* __restrict__ pL,
                                                    float* __restrict__ out) {
    int tile = blockIdx.x, batch = blockIdx.y;
    int nparts = (2 * tile + 9) >> 3;
    int a = tile >> 2, r = tile & 3;
    int slot0 = batch * PPB + 2 * a * (a + 1) + r * (a + 1);
    int t = threadIdx.x;
    int off = t * 32;                 // thread owns 32 contiguous floats
    int row = off >> 6;

    float L = 0.f;
    float4 acc[8];
#pragma unroll
    for (int i = 0; i < 8; i++) acc[i] = (float4){0.f, 0.f, 0.f, 0.f};

    for (int p = 0; p < nparts; ++p) {
        int slot = slot0 + p;
        L += pL[(size_t)slot * 128 + row];
        const float4* src = reinterpret_cast<const float4*>(pO + (size_t)slot * 8192 + off);
#pragma unroll
        for (int i = 0; i < 8; i++) {
            float4 v = src[i];
            acc[i].x += v.x; acc[i].y += v.y; acc[i].z += v.z; acc[i].w += v.w;
        }
    }
    float inv = 1.0f / L;
    float4* dstp = reinterpret_cast<float4*>(out + (size_t)batch * TLEN * HD +
                                             (size_t)tile * 128 * HD + off);
#pragma unroll
    for (int i = 0; i < 8; i++) {
        float4 v; v.x = acc[i].x * inv; v.y = acc[i].y * inv; v.z = acc[i].z * inv; v.w = acc[i].w * inv;
        dstp[i] = v;
    }
}

extern "C" void kernel_launch(void* const* d_in, const int* in_sizes, int n_in,
                              void* d_out, int out_size, void* d_ws, size_t ws_size,
                              hipStream_t stream) {
    const float* x  = (const float*)d_in[0];
    const float* Wk = (const float*)d_in[1];
    const float* bk = (const float*)d_in[2];
    const float* Wq = (const float*)d_in[3];
    const float* bq = (const float*)d_in[4];
    const float* Wv = (const float*)d_in[5];
    const float* bv = (const float*)d_in[6];
    float* out = (float*)d_out;

    const size_t nrow = (size_t)NB * TLEN;            // 16384
    short* ko = (short*)d_ws;                         // bf16 k (pre-scaled)      2 MB
    short* qo = ko + nrow * HD;                       // bf16 q                   2 MB
    short* vt = qo + nrow * HD;                       // bf16 v^T [4][64][4096]   2 MB
    short* wt = vt + nrow * HD;                       // bf16 wt frag-major       384 KB
    float* pO = (float*)(wt + 3 * 64 * 1024);         // partial O [4*144][128][64]
    float* pL = pO + (size_t)NB * PPB * 8192;         // partial l [4*144][128]
    size_t need = (size_t)((char*)(pL + (size_t)NB * PPB * 128) - (char*)d_ws);

    prep_w<<<768, 256, 0, stream>>>(Wk, Wq, Wv, wt);
    proj<<<512, 256, 0, stream>>>(x, bk, bq, bv, wt, ko, qo, vt);
    if (ws_size >= need) {
        attn_kern<1><<<dim3(PPB, NB), 256, 0, stream>>>(ko, qo, vt, pO, pL);
        attn_combine<<<dim3(32, NB), 256, 0, stream>>>(pO, pL, out);
    } else {
        attn_kern<0><<<dim3(32, NB), 256, 0, stream>>>(ko, qo, vt, out, nullptr);
    }
}